// Round 3
// baseline (709.626 us; speedup 1.0000x reference)
//
#include <hip/hip_runtime.h>
#include <stdint.h>

typedef unsigned short ushort_t;
typedef __attribute__((ext_vector_type(8))) __bf16 bf16x8;
typedef __attribute__((ext_vector_type(4))) float floatx4;
typedef __attribute__((ext_vector_type(4))) unsigned short ushort4v;
typedef __attribute__((ext_vector_type(8))) unsigned short ushort8v;

// ---------------- constants ----------------
#define TT 8192L   // tokens = B*L
#define LB 4096L   // tokens per batch
#define DD 768L
#define DI 3072L
#define NH 48L
#define R3C 256L
#define R2C 1024L
#define NP 6272L   // padded proj width (2*DI + NH = 6192 -> 49*128)

// ---------------- helpers ----------------
__device__ __forceinline__ float b2f(ushort_t u) {
  union { unsigned u32; float f; } v; v.u32 = ((unsigned)u) << 16; return v.f;
}
__device__ __forceinline__ ushort_t f2b(float f) {
  union { float f; unsigned u32; } v; v.f = f;
  unsigned r = v.u32 + 0x7FFFu + ((v.u32 >> 16) & 1u);
  return (ushort_t)(r >> 16);
}
// async global->LDS, 16B/lane; LDS base wave-uniform. Only in 4-wave k_gemm.
__device__ __forceinline__ void g2l16(const void* g, void* l) {
  __builtin_amdgcn_global_load_lds(
      (const __attribute__((address_space(1))) unsigned int*)g,
      (__attribute__((address_space(3))) unsigned int*)l, 16, 0, 0);
}

// ---------------- transpose f32 -> bf16: dst[n][k] = src[k][n], zero-pad n>=N ----------------
__global__ __launch_bounds__(256) void k_tr(const float* __restrict__ src,
                                            ushort_t* __restrict__ dst,
                                            int K, int N) {
  __shared__ float tile[64][65];
  int k0 = blockIdx.x * 64, n0 = blockIdx.y * 64;
  int c = threadIdx.x & 63, r4 = threadIdx.x >> 6;
#pragma unroll
  for (int s = 0; s < 16; s++) {
    int r = s * 4 + r4;
    int n = n0 + c;
    tile[c][r] = (n < N) ? src[(long)(k0 + r) * N + n] : 0.0f;
  }
  __syncthreads();
#pragma unroll
  for (int s = 0; s < 16; s++) {
    int r = s * 4 + r4;
    dst[(long)(n0 + r) * K + k0 + c] = f2b(tile[r][c]);
  }
}

// ---------------- RMSNorm: f32 in -> bf16 out ----------------
__global__ __launch_bounds__(256) void k_rms(const float* __restrict__ x,
                                             const float* __restrict__ w,
                                             ushort_t* __restrict__ out) {
  int t = blockIdx.x, tid = threadIdx.x;
  int lane = tid & 63, wid = tid >> 6;
  const float* xr = x + (long)t * DD;
  float v0 = xr[tid], v1 = xr[tid + 256], v2 = xr[tid + 512];
  float ss = v0 * v0 + v1 * v1 + v2 * v2;
  for (int o = 32; o; o >>= 1) ss += __shfl_down(ss, o);
  __shared__ float red[4];
  if (lane == 0) red[wid] = ss;
  __syncthreads();
  float tot = red[0] + red[1] + red[2] + red[3];
  float rr = rsqrtf(tot / 768.0f + 1e-5f);
  ushort_t* orow = out + (long)t * DD;
  orow[tid]       = f2b(v0 * rr * w[tid]);
  orow[tid + 256] = f2b(v1 * rr * w[tid + 256]);
  orow[tid + 512] = f2b(v2 * rr * w[tid + 512]);
}

// ---------------- RMSNorm2 (bf16 x1) + router (f32 W_router [768][8]) ----------------
__global__ __launch_bounds__(256) void k_rms2_router(const ushort_t* __restrict__ x1,
                                                     const float* __restrict__ w,
                                                     const float* __restrict__ wr,
                                                     ushort_t* __restrict__ x2n,
                                                     float* __restrict__ wrt) {
  int t = blockIdx.x, tid = threadIdx.x;
  int lane = tid & 63, wid = tid >> 6;
  const ushort_t* xr = x1 + (long)t * DD;
  float v[3];
  int dd[3] = {tid, tid + 256, tid + 512};
  v[0] = b2f(xr[dd[0]]); v[1] = b2f(xr[dd[1]]); v[2] = b2f(xr[dd[2]]);
  float ss = v[0] * v[0] + v[1] * v[1] + v[2] * v[2];
  for (int o = 32; o; o >>= 1) ss += __shfl_down(ss, o);
  __shared__ float red[4];
  __shared__ float wred[4][8];
  __shared__ float slog[8];
  if (lane == 0) red[wid] = ss;
  __syncthreads();
  float tot = red[0] + red[1] + red[2] + red[3];
  float rr = rsqrtf(tot / 768.0f + 1e-5f);
  float p[8] = {0, 0, 0, 0, 0, 0, 0, 0};
  ushort_t* orow = x2n + (long)t * DD;
#pragma unroll
  for (int i = 0; i < 3; i++) {
    float xnv = v[i] * rr * w[dd[i]];
    orow[dd[i]] = f2b(xnv);
    const float* wrow = wr + (long)dd[i] * 8;
#pragma unroll
    for (int e = 0; e < 8; e++) p[e] += xnv * wrow[e];
  }
#pragma unroll
  for (int e = 0; e < 8; e++) {
    float s = p[e];
    for (int o = 32; o; o >>= 1) s += __shfl_down(s, o);
    if (lane == 0) wred[wid][e] = s;
  }
  __syncthreads();
  if (tid < 8)
    slog[tid] = (wred[0][tid] + wred[1][tid] + wred[2][tid] + wred[3][tid]) * 2.0f; // 1/temp
  __syncthreads();
  if (tid == 0) {
    float l[8];
#pragma unroll
    for (int e = 0; e < 8; e++) l[e] = slog[e];
    int e0 = 0; float b0 = l[0];
#pragma unroll
    for (int e = 1; e < 8; e++) if (l[e] > b0) { b0 = l[e]; e0 = e; }
    int e1 = -1; float b1 = -1e30f;
#pragma unroll
    for (int e = 0; e < 8; e++) if (e != e0 && l[e] > b1) { b1 = l[e]; e1 = e; }
    float ex = __expf(b1 - b0);
    float pd = 1.0f / (1.0f + ex);
    float* wo = wrt + (long)t * 8;
#pragma unroll
    for (int e = 0; e < 8; e++) wo[e] = 0.0f;
    wo[e0] = pd;
    wo[e1] = ex * pd;
  }
}

// ---------------- alpha = exp(-softplus(dt + bias)); batch-local [h][t] ----------------
__global__ __launch_bounds__(256) void k_alpha(const ushort_t* __restrict__ proj,
                                               const float* __restrict__ dtb,
                                               float* __restrict__ alpha) {
  int gid = blockIdx.x * 256 + threadIdx.x;   // < 196608 = 4096*48
  int tg = gid / 48;
  int h = gid - tg * 48;
  float dt = b2f(proj[(long)tg * NP + 2 * DI + h]) + dtb[h];
  float sp = (dt > 20.0f) ? dt : log1pf(__expf(dt));
  alpha[(long)h * LB + tg] = __expf(-sp);
}

// stage one 64-token x 64-dim head-slice tile into LDS via registers.
// lds[tt*64 + lane] == src[tt][lane]
__device__ __forceinline__ void stage_tile(const ushort_t* __restrict__ g, long rowstride,
                                           ushort_t* __restrict__ lds, int lane) {
  const int lrow = lane >> 3;
  const int dcol = (lane & 7) * 8;
#pragma unroll
  for (int c8 = 0; c8 < 8; c8++) {
    ushort8v v = *(const ushort8v*)(g + (long)(c8 * 8 + lrow) * rowstride + dcol);
    *(ushort8v*)&lds[(c8 * 64 + lane) * 8] = v;
  }
}

// ---------------- scan phase 1 (batch-local): per-chunk summaries ----------------
__global__ __launch_bounds__(64) void k_scan1(const ushort_t* __restrict__ proj,
                                              const float* __restrict__ alpha,
                                              float* __restrict__ ssum,
                                              float* __restrict__ asum) {
  __shared__ __align__(16) ushort_t u_lds[64 * 64];
  __shared__ float s_alpha[512];
  const int lane = threadIdx.x;
  const int idx = blockIdx.x;          // h*8 + c, 384 blocks
  const int c = idx & 7;
  const int h = idx >> 3;
  const float* arow = alpha + (long)h * LB + (long)c * 512;
#pragma unroll
  for (int k = 0; k < 8; k++) s_alpha[lane + 64 * k] = arow[lane + 64 * k];
  const ushort_t* ug = proj + (long)c * 512 * NP + (long)h * 64;
  float s = 0.0f, A = 1.0f;
  for (int tile = 0; tile < 8; tile++) {
    stage_tile(ug + (long)tile * 64 * NP, NP, u_lds, lane);
    __syncthreads();
#pragma unroll
    for (int tt = 0; tt < 64; tt++) {
      float a = s_alpha[tile * 64 + tt];
      float u = b2f(u_lds[tt * 64 + lane]);
      s = fmaf(a, s, u);
      A *= a;
    }
    __syncthreads();
  }
  ssum[(long)idx * 64 + lane] = s;
  if (lane == 0) asum[idx] = A;
}

// ---------------- scan phase 2: chunk carries (48 blocks) ----------------
__global__ __launch_bounds__(64) void k_scan2(const float* __restrict__ ssum,
                                              const float* __restrict__ asum,
                                              float* __restrict__ carry) {
  int h = blockIdx.x, lane = threadIdx.x;
  float cv = 0.0f;
#pragma unroll
  for (int c = 0; c < 8; c++) {
    carry[((long)h * 8 + c) * 64 + lane] = cv;
    float A = asum[h * 8 + c];
    float s = ssum[((long)h * 8 + c) * 64 + lane];
    cv = A * cv + s;
  }
}

// ---------------- scan phase 3 (batch-local): scan + silu gate + scaled tanh ----------------
__global__ __launch_bounds__(64) void k_scan3(const ushort_t* __restrict__ proj,
                                              const float* __restrict__ alpha,
                                              const float* __restrict__ carry,
                                              ushort_t* __restrict__ y) {
  __shared__ __align__(16) ushort_t u_lds[64 * 64];
  __shared__ __align__(16) ushort_t z_lds[64 * 64];
  __shared__ float s_alpha[512];
  const int lane = threadIdx.x;
  const int idx = blockIdx.x;          // h*8 + c
  const int c = idx & 7;
  const int h = idx >> 3;
  const float* arow = alpha + (long)h * LB + (long)c * 512;
#pragma unroll
  for (int k = 0; k < 8; k++) s_alpha[lane + 64 * k] = arow[lane + 64 * k];
  const ushort_t* ug = proj + (long)c * 512 * NP + (long)h * 64;
  const ushort_t* zg = ug + DI;
  ushort_t* yg = y + (long)c * 512 * DI + (long)h * 64;
  float hs = carry[(long)idx * 64 + lane];
  for (int tile = 0; tile < 8; tile++) {
    stage_tile(ug + (long)tile * 64 * NP, NP, u_lds, lane);
    stage_tile(zg + (long)tile * 64 * NP, NP, z_lds, lane);
    __syncthreads();
#pragma unroll
    for (int tt = 0; tt < 64; tt++) {
      float a = s_alpha[tile * 64 + tt];
      float u = b2f(u_lds[tt * 64 + lane]);
      hs = fmaf(a, hs, u);
      float zv = b2f(z_lds[tt * 64 + lane]);
      float sig = 1.0f / (1.0f + __expf(-zv));
      float yv = hs * zv * sig;
      yv = 10.0f * tanhf(yv * 0.1f);
      yg[(long)(tile * 64 + tt) * DI + lane] = f2b(yv);
    }
    __syncthreads();
  }
}

// ---------------- A_big[t][e*256+r] = w[t][e]*lat[t][r] ----------------
__global__ __launch_bounds__(256) void k_abig(const ushort_t* __restrict__ lat,
                                              const float* __restrict__ wrt,
                                              ushort_t* __restrict__ abig) {
  long gid = (long)blockIdx.x * 256 + threadIdx.x;
  long idx = gid * 4;
  int t = (int)(idx >> 11);
  int off = (int)(idx & 2047);
  int e = off >> 8, r = off & 255;
  float wv = wrt[(long)t * 8 + e];
  ushort4v lv = *(const ushort4v*)(lat + (long)t * R3C + r);
  ushort4v ov;
  ov.x = f2b(wv * b2f(lv.x));
  ov.y = f2b(wv * b2f(lv.y));
  ov.z = f2b(wv * b2f(lv.z));
  ov.w = f2b(wv * b2f(lv.w));
  *(ushort4v*)(abig + (long)t * 2048 + off) = ov;
}

// ---------------- bf16 GEMM, B^T input (m97 structure) ----------------
// MODE 0: bf16 C = A@B            MODE 2: bf16 C = 10*tanh(0.1*A@B)
// MODE 1: bf16 C = resf + ls*(A@B)  (resf,ls f32)
// MODE 3: f32  C = b2f(resb) + ls*(A@B)
template <int MODE>
__global__ __launch_bounds__(256, 2) void k_gemm(const ushort_t* __restrict__ A,   // [M][K]
                                                 const ushort_t* __restrict__ Bt,  // [N][K]
                                                 void* __restrict__ Cout, int K, int ldc,
                                                 const float* __restrict__ resf,
                                                 const ushort_t* __restrict__ resb,
                                                 const float* __restrict__ ls) {
  __shared__ __align__(16) ushort_t sA[128 * 32];
  __shared__ __align__(16) ushort_t sB[128 * 32];
  const int tid = threadIdx.x;
  const int lane = tid & 63, wid = tid >> 6;
  const int lm = lane & 15, q = lane >> 4;
  const int wm = wid >> 1, wn = wid & 1;
  const long row0 = (long)blockIdx.x * 128;
  const long col0 = (long)blockIdx.y * 128;

  floatx4 acc[4][4] = {};

  const int srow = wid * 32 + (lane >> 2);
  const int skoff = (lane & 3) * 8;
  const ushort_t* Ag0 = A + (row0 + srow) * (long)K + skoff;
  const ushort_t* Ag1 = Ag0 + 16L * K;
  const ushort_t* Bg0 = Bt + (col0 + srow) * (long)K + skoff;
  const ushort_t* Bg1 = Bg0 + 16L * K;
  ushort_t* sA0 = sA + wid * 1024;
  ushort_t* sB0 = sB + wid * 1024;

  for (int k0 = 0; k0 < K; k0 += 32) {
    g2l16(Ag0 + k0, sA0);
    g2l16(Ag1 + k0, sA0 + 512);
    g2l16(Bg0 + k0, sB0);
    g2l16(Bg1 + k0, sB0 + 512);
    __syncthreads();
    bf16x8 af[4], bfr[4];
#pragma unroll
    for (int i = 0; i < 4; i++)
      af[i] = *(const bf16x8*)(const void*)&sA[(wm * 64 + i * 16 + lm) * 32 + q * 8];
#pragma unroll
    for (int j = 0; j < 4; j++)
      bfr[j] = *(const bf16x8*)(const void*)&sB[(wn * 64 + j * 16 + lm) * 32 + q * 8];
#pragma unroll
    for (int i = 0; i < 4; i++)
#pragma unroll
      for (int j = 0; j < 4; j++)
        acc[i][j] = __builtin_amdgcn_mfma_f32_16x16x32_bf16(af[i], bfr[j], acc[i][j], 0, 0, 0);
    __syncthreads();
  }
#pragma unroll
  for (int i = 0; i < 4; i++) {
#pragma unroll
    for (int r = 0; r < 4; r++) {
      long row = row0 + wm * 64 + i * 16 + q * 4 + r;
#pragma unroll
      for (int j = 0; j < 4; j++) {
        long col = col0 + wn * 64 + j * 16 + lm;
        float v = acc[i][j][r];
        if (MODE == 0) {
          ((ushort_t*)Cout)[row * (long)ldc + col] = f2b(v);
        } else if (MODE == 2) {
          ((ushort_t*)Cout)[row * (long)ldc + col] = f2b(10.0f * tanhf(v * 0.1f));
        } else if (MODE == 1) {
          float rv = resf[row * DD + col];
          ((ushort_t*)Cout)[row * (long)ldc + col] = f2b(rv + ls[col] * v);
        } else {
          float rv = b2f(resb[row * DD + col]);
          ((float*)Cout)[row * (long)ldc + col] = rv + ls[col] * v;
        }
      }
    }
  }
}

// ---------------- workspace layout (bytes), peak 123.5 MB ----------------
#define OFF_WINT   0L                          // 6272*768*2   = 9,633,792
#define OFF_WOUTT  9633792L                    // 768*3072*2   = 4,718,592
#define OFF_WDNT   14352384L                   // 256*768*2    = 393,216
#define OFF_WUPT   14745600L                   // 768*1024*2   = 1,572,864
#define OFF_GT     16318464L                   // 1024*2048*2  = 4,194,304
#define OFF_X1     20512768L                   // 8192*768*2   = 12,582,912
#define OFF_WRT    33095680L                   // 8192*8*4     = 262,144
#define OFF_ALPHA  33357824L                   // 48*4096*4    = 786,432
#define OFF_SSUM   34144256L                   // 384*64*4     = 98,304
#define OFF_ASUM   34242560L                   // 384*4        = 1,536
#define OFF_CARRY  34244096L                   // 384*64*4     = 98,304
#define OFF_XN     34342400L                   // 8192*768*2   = 12,582,912 (alias x2n)
#define OFF_Y      46925312L                   // 4096*3072*2  = 25,165,824 (alias moe 16.8MB)
#define OFF_PROJ   72091136L                   // 4096*6272*2  = 51,380,224 (alias abig+lat 37.7MB)
#define OFF_ABIG   OFF_PROJ
#define OFF_LAT    (OFF_PROJ + 33554432L)
#define OFF_X2N    OFF_XN
#define OFF_MOE    OFF_Y
#define WS_NEEDED  123471360L

extern "C" void kernel_launch(void* const* d_in, const int* in_sizes, int n_in,
                              void* d_out, int out_size, void* d_ws, size_t ws_size,
                              hipStream_t stream) {
  // ALL reference inputs are float32; output is float32.
  const float* x     = (const float*)d_in[0];
  const float* rms1w = (const float*)d_in[1];
  const float* W_in  = (const float*)d_in[2];
  const float* dtb   = (const float*)d_in[3];
  const float* W_out = (const float*)d_in[4];
  const float* ls1   = (const float*)d_in[5];
  const float* rms2w = (const float*)d_in[6];
  const float* W_dn  = (const float*)d_in[7];
  const float* W_rtr = (const float*)d_in[8];
  const float* G     = (const float*)d_in[9];
  const float* W_up  = (const float*)d_in[10];
  const float* ls2   = (const float*)d_in[11];
  if (ws_size < (size_t)WS_NEEDED) return;  // diagnostic guard: output stays 0 => absmax ~5.06

  char* ws = (char*)d_ws;
  ushort_t* W_inT  = (ushort_t*)(ws + OFF_WINT);
  ushort_t* W_outT = (ushort_t*)(ws + OFF_WOUTT);
  ushort_t* W_dnT  = (ushort_t*)(ws + OFF_WDNT);
  ushort_t* W_upT  = (ushort_t*)(ws + OFF_WUPT);
  ushort_t* GT     = (ushort_t*)(ws + OFF_GT);
  ushort_t* x1     = (ushort_t*)(ws + OFF_X1);
  float*    wrt    = (float*)(ws + OFF_WRT);
  float*    alpha  = (float*)(ws + OFF_ALPHA);
  float*    ssum   = (float*)(ws + OFF_SSUM);
  float*    asum   = (float*)(ws + OFF_ASUM);
  float*    carry  = (float*)(ws + OFF_CARRY);
  ushort_t* xn     = (ushort_t*)(ws + OFF_XN);
  ushort_t* y      = (ushort_t*)(ws + OFF_Y);
  ushort_t* proj   = (ushort_t*)(ws + OFF_PROJ);
  ushort_t* abig   = (ushort_t*)(ws + OFF_ABIG);
  ushort_t* lat    = (ushort_t*)(ws + OFF_LAT);
  ushort_t* x2n    = (ushort_t*)(ws + OFF_X2N);
  ushort_t* moe    = (ushort_t*)(ws + OFF_MOE);
  float*    outp   = (float*)d_out;

  // weight transposes (f32 -> bf16), [K][N] -> [N][K]; W_in rows padded 6192->6272 w/ zeros
  k_tr<<<dim3(12, 98), 256, 0, stream>>>(W_in, W_inT, 768, 6192);
  k_tr<<<dim3(48, 12), 256, 0, stream>>>(W_out, W_outT, 3072, 768);
  k_tr<<<dim3(12, 4), 256, 0, stream>>>(W_dn, W_dnT, 768, 256);
  k_tr<<<dim3(16, 12), 256, 0, stream>>>(W_up, W_upT, 1024, 768);
  k_tr<<<dim3(32, 16), 256, 0, stream>>>(G, GT, 2048, 1024);

  k_rms<<<8192, 256, 0, stream>>>(x, rms1w, xn);

  for (int b = 0; b < 2; b++) {
    const ushort_t* xnb = xn + (long)b * LB * DD;
    k_gemm<0><<<dim3(32, 49), 256, 0, stream>>>(xnb, W_inT, proj, 768, (int)NP,
                                                nullptr, nullptr, nullptr);
    k_alpha<<<768, 256, 0, stream>>>(proj, dtb, alpha);
    k_scan1<<<384, 64, 0, stream>>>(proj, alpha, ssum, asum);
    k_scan2<<<48, 64, 0, stream>>>(ssum, asum, carry);
    k_scan3<<<384, 64, 0, stream>>>(proj, alpha, carry, y);
    k_gemm<1><<<dim3(32, 6), 256, 0, stream>>>(y, W_outT, x1 + (long)b * LB * DD, 3072, 768,
                                               x + (long)b * LB * DD, nullptr, ls1);
  }

  k_rms2_router<<<8192, 256, 0, stream>>>(x1, rms2w, W_rtr, x2n, wrt);
  k_gemm<2><<<dim3(64, 2), 256, 0, stream>>>(x2n, W_dnT, lat, 768, 256,
                                             nullptr, nullptr, nullptr);
  k_abig<<<16384, 256, 0, stream>>>(lat, wrt, abig);
  k_gemm<0><<<dim3(64, 8), 256, 0, stream>>>(abig, GT, moe, 2048, 1024,
                                             nullptr, nullptr, nullptr);
  k_gemm<3><<<dim3(64, 6), 256, 0, stream>>>(moe, W_upT, outp, 1024, 768,
                                             nullptr, x1, ls2);
}

// Round 4
// 605.175 us; speedup vs baseline: 1.1726x; 1.1726x over previous
//
#include <hip/hip_runtime.h>
#include <stdint.h>

typedef unsigned short ushort_t;
typedef __attribute__((ext_vector_type(8))) __bf16 bf16x8;
typedef __attribute__((ext_vector_type(4))) float floatx4;
typedef __attribute__((ext_vector_type(4))) unsigned short ushort4v;
typedef __attribute__((ext_vector_type(8))) unsigned short ushort8v;

// ---------------- constants ----------------
#define TT 8192L   // tokens = B*L
#define LB 4096L   // tokens per batch
#define DD 768L
#define DI 3072L
#define NH 48L
#define R3C 256L
#define R2C 1024L
#define NP 6272L   // padded proj width (2*DI + NH = 6192 -> 49*128)
#define NCH 64L    // scan chunks per batch
#define CHS 64L    // chunk length (tokens)

// ---------------- helpers ----------------
__device__ __forceinline__ float b2f(ushort_t u) {
  union { unsigned u32; float f; } v; v.u32 = ((unsigned)u) << 16; return v.f;
}
__device__ __forceinline__ ushort_t f2b(float f) {
  union { float f; unsigned u32; } v; v.f = f;
  unsigned r = v.u32 + 0x7FFFu + ((v.u32 >> 16) & 1u);
  return (ushort_t)(r >> 16);
}
__device__ __forceinline__ float fast_tanh(float x) {
  // tanh(x) = 1 - 2/(exp(2x)+1); exp overflow -> +/-1 correctly
  float e = __expf(2.0f * x);
  return 1.0f - 2.0f / (e + 1.0f);
}
// async global->LDS, 16B/lane; LDS base wave-uniform. Only in 4-wave k_gemm.
__device__ __forceinline__ void g2l16(const void* g, void* l) {
  __builtin_amdgcn_global_load_lds(
      (const __attribute__((address_space(1))) unsigned int*)g,
      (__attribute__((address_space(3))) unsigned int*)l, 16, 0, 0);
}

// ---------------- transpose f32 -> bf16: dst[n][k] = src[k][n], zero-pad n>=N ----------------
__global__ __launch_bounds__(256) void k_tr(const float* __restrict__ src,
                                            ushort_t* __restrict__ dst,
                                            int K, int N) {
  __shared__ float tile[64][65];
  int k0 = blockIdx.x * 64, n0 = blockIdx.y * 64;
  int c = threadIdx.x & 63, r4 = threadIdx.x >> 6;
#pragma unroll
  for (int s = 0; s < 16; s++) {
    int r = s * 4 + r4;
    int n = n0 + c;
    tile[c][r] = (n < N) ? src[(long)(k0 + r) * N + n] : 0.0f;
  }
  __syncthreads();
#pragma unroll
  for (int s = 0; s < 16; s++) {
    int r = s * 4 + r4;
    dst[(long)(n0 + r) * K + k0 + c] = f2b(tile[r][c]);
  }
}

// ---------------- RMSNorm: f32 in -> bf16 out ----------------
__global__ __launch_bounds__(256) void k_rms(const float* __restrict__ x,
                                             const float* __restrict__ w,
                                             ushort_t* __restrict__ out) {
  int t = blockIdx.x, tid = threadIdx.x;
  int lane = tid & 63, wid = tid >> 6;
  const float* xr = x + (long)t * DD;
  float v0 = xr[tid], v1 = xr[tid + 256], v2 = xr[tid + 512];
  float ss = v0 * v0 + v1 * v1 + v2 * v2;
  for (int o = 32; o; o >>= 1) ss += __shfl_down(ss, o);
  __shared__ float red[4];
  if (lane == 0) red[wid] = ss;
  __syncthreads();
  float tot = red[0] + red[1] + red[2] + red[3];
  float rr = rsqrtf(tot / 768.0f + 1e-5f);
  ushort_t* orow = out + (long)t * DD;
  orow[tid]       = f2b(v0 * rr * w[tid]);
  orow[tid + 256] = f2b(v1 * rr * w[tid + 256]);
  orow[tid + 512] = f2b(v2 * rr * w[tid + 512]);
}

// ---------------- RMSNorm2 (bf16 x1) + router (f32 W_router [768][8]) ----------------
__global__ __launch_bounds__(256) void k_rms2_router(const ushort_t* __restrict__ x1,
                                                     const float* __restrict__ w,
                                                     const float* __restrict__ wr,
                                                     ushort_t* __restrict__ x2n,
                                                     float* __restrict__ wrt) {
  int t = blockIdx.x, tid = threadIdx.x;
  int lane = tid & 63, wid = tid >> 6;
  const ushort_t* xr = x1 + (long)t * DD;
  float v[3];
  int dd[3] = {tid, tid + 256, tid + 512};
  v[0] = b2f(xr[dd[0]]); v[1] = b2f(xr[dd[1]]); v[2] = b2f(xr[dd[2]]);
  float ss = v[0] * v[0] + v[1] * v[1] + v[2] * v[2];
  for (int o = 32; o; o >>= 1) ss += __shfl_down(ss, o);
  __shared__ float red[4];
  __shared__ float wred[4][8];
  __shared__ float slog[8];
  if (lane == 0) red[wid] = ss;
  __syncthreads();
  float tot = red[0] + red[1] + red[2] + red[3];
  float rr = rsqrtf(tot / 768.0f + 1e-5f);
  float p[8] = {0, 0, 0, 0, 0, 0, 0, 0};
  ushort_t* orow = x2n + (long)t * DD;
#pragma unroll
  for (int i = 0; i < 3; i++) {
    float xnv = v[i] * rr * w[dd[i]];
    orow[dd[i]] = f2b(xnv);
    const float* wrow = wr + (long)dd[i] * 8;
#pragma unroll
    for (int e = 0; e < 8; e++) p[e] += xnv * wrow[e];
  }
#pragma unroll
  for (int e = 0; e < 8; e++) {
    float s = p[e];
    for (int o = 32; o; o >>= 1) s += __shfl_down(s, o);
    if (lane == 0) wred[wid][e] = s;
  }
  __syncthreads();
  if (tid < 8)
    slog[tid] = (wred[0][tid] + wred[1][tid] + wred[2][tid] + wred[3][tid]) * 2.0f; // 1/temp
  __syncthreads();
  if (tid == 0) {
    float l[8];
#pragma unroll
    for (int e = 0; e < 8; e++) l[e] = slog[e];
    int e0 = 0; float b0 = l[0];
#pragma unroll
    for (int e = 1; e < 8; e++) if (l[e] > b0) { b0 = l[e]; e0 = e; }
    int e1 = -1; float b1 = -1e30f;
#pragma unroll
    for (int e = 0; e < 8; e++) if (e != e0 && l[e] > b1) { b1 = l[e]; e1 = e; }
    float ex = __expf(b1 - b0);
    float pd = 1.0f / (1.0f + ex);
    float* wo = wrt + (long)t * 8;
#pragma unroll
    for (int e = 0; e < 8; e++) wo[e] = 0.0f;
    wo[e0] = pd;
    wo[e1] = ex * pd;
  }
}

// ---------------- alpha = exp(-softplus(dt + bias)); batch-local [h][t] ----------------
__global__ __launch_bounds__(256) void k_alpha(const ushort_t* __restrict__ proj,
                                               const float* __restrict__ dtb,
                                               float* __restrict__ alpha) {
  int gid = blockIdx.x * 256 + threadIdx.x;   // < 196608 = 4096*48
  int tg = gid / 48;
  int h = gid - tg * 48;
  float dt = b2f(proj[(long)tg * NP + 2 * DI + h]) + dtb[h];
  float sp = (dt > 20.0f) ? dt : log1pf(__expf(dt));
  alpha[(long)h * LB + tg] = __expf(-sp);
}

// stage one 64-token x 64-dim head-slice tile into LDS via registers.
// lds[tt*64 + dim] == src[tt][dim]
__device__ __forceinline__ void stage_tile(const ushort_t* __restrict__ g, long rowstride,
                                           ushort_t* __restrict__ lds, int lane) {
  const int lrow = lane >> 3;
  const int dcol = (lane & 7) * 8;
#pragma unroll
  for (int c8 = 0; c8 < 8; c8++) {
    ushort8v v = *(const ushort8v*)(g + (long)(c8 * 8 + lrow) * rowstride + dcol);
    *(ushort8v*)&lds[(c8 * 64 + lane) * 8] = v;
  }
}

// ---------------- scan phase 1: per-chunk (64-token) summaries, 3072 blocks ----------------
__global__ __launch_bounds__(64) void k_scan1(const ushort_t* __restrict__ proj,
                                              const float* __restrict__ alpha,
                                              float* __restrict__ ssum,
                                              float* __restrict__ asum) {
  __shared__ __align__(16) ushort_t u_lds[64 * 64];
  __shared__ float s_alpha[64];
  const int lane = threadIdx.x;
  const int idx = blockIdx.x;          // h*64 + c
  const int c = idx & 63;
  const int h = idx >> 6;
  s_alpha[lane] = alpha[(long)h * LB + (long)c * CHS + lane];
  const ushort_t* ug = proj + (long)c * CHS * NP + (long)h * 64;
  stage_tile(ug, NP, u_lds, lane);
  __syncthreads();
  float s = 0.0f, A = 1.0f;
#pragma unroll
  for (int tt = 0; tt < 64; tt++) {
    float a = s_alpha[tt];
    float u = b2f(u_lds[tt * 64 + lane]);
    s = fmaf(a, s, u);
    A *= a;
  }
  ssum[(long)idx * 64 + lane] = s;
  if (lane == 0) asum[idx] = A;
}

// ---------------- scan phase 2: chunk carries (48 blocks, 64-step serial) ----------------
__global__ __launch_bounds__(64) void k_scan2(const float* __restrict__ ssum,
                                              const float* __restrict__ asum,
                                              float* __restrict__ carry) {
  int h = blockIdx.x, lane = threadIdx.x;
  float cv = 0.0f;
  for (int c = 0; c < 64; c++) {
    carry[((long)h * 64 + c) * 64 + lane] = cv;
    float A = asum[h * 64 + c];
    float s = ssum[((long)h * 64 + c) * 64 + lane];
    cv = A * cv + s;
  }
}

// ---------------- scan phase 3: scan + silu gate + scaled tanh, 3072 blocks ----------------
__global__ __launch_bounds__(64) void k_scan3(const ushort_t* __restrict__ proj,
                                              const float* __restrict__ alpha,
                                              const float* __restrict__ carry,
                                              ushort_t* __restrict__ y) {
  __shared__ __align__(16) ushort_t u_lds[64 * 64];
  __shared__ __align__(16) ushort_t z_lds[64 * 64];
  __shared__ float s_alpha[64];
  const int lane = threadIdx.x;
  const int idx = blockIdx.x;          // h*64 + c
  const int c = idx & 63;
  const int h = idx >> 6;
  s_alpha[lane] = alpha[(long)h * LB + (long)c * CHS + lane];
  const ushort_t* ug = proj + (long)c * CHS * NP + (long)h * 64;
  const ushort_t* zg = ug + DI;
  ushort_t* yg = y + (long)c * CHS * DI + (long)h * 64;
  stage_tile(ug, NP, u_lds, lane);
  stage_tile(zg, NP, z_lds, lane);
  __syncthreads();
  float hs = carry[(long)idx * 64 + lane];
#pragma unroll
  for (int tt = 0; tt < 64; tt++) {
    float a = s_alpha[tt];
    float u = b2f(u_lds[tt * 64 + lane]);
    hs = fmaf(a, hs, u);
    float zv = b2f(z_lds[tt * 64 + lane]);
    float sig = 1.0f / (1.0f + __expf(-zv));
    float yv = hs * zv * sig;
    yv = 10.0f * fast_tanh(yv * 0.1f);
    yg[(long)tt * DI + lane] = f2b(yv);
  }
}

// ---------------- A_big[t][e*256+r] = w[t][e]*lat[t][r] ----------------
__global__ __launch_bounds__(256) void k_abig(const ushort_t* __restrict__ lat,
                                              const float* __restrict__ wrt,
                                              ushort_t* __restrict__ abig) {
  long gid = (long)blockIdx.x * 256 + threadIdx.x;
  long idx = gid * 4;
  int t = (int)(idx >> 11);
  int off = (int)(idx & 2047);
  int e = off >> 8, r = off & 255;
  float wv = wrt[(long)t * 8 + e];
  ushort4v lv = *(const ushort4v*)(lat + (long)t * R3C + r);
  ushort4v ov;
  ov.x = f2b(wv * b2f(lv.x));
  ov.y = f2b(wv * b2f(lv.y));
  ov.z = f2b(wv * b2f(lv.z));
  ov.w = f2b(wv * b2f(lv.w));
  *(ushort4v*)(abig + (long)t * 2048 + off) = ov;
}

// ---------------- bf16 GEMM, B^T input (m97 structure) ----------------
// MODE 0: bf16 C = A@B            MODE 2: bf16 C = 10*tanh(0.1*A@B)
// MODE 1: bf16 C = resf + ls*(A@B)  (resf,ls f32)
// MODE 3: f32  C = b2f(resb) + ls*(A@B)
template <int MODE>
__global__ __launch_bounds__(256, 2) void k_gemm(const ushort_t* __restrict__ A,   // [M][K]
                                                 const ushort_t* __restrict__ Bt,  // [N][K]
                                                 void* __restrict__ Cout, int K, int ldc,
                                                 const float* __restrict__ resf,
                                                 const ushort_t* __restrict__ resb,
                                                 const float* __restrict__ ls) {
  __shared__ __align__(16) ushort_t sA[128 * 32];
  __shared__ __align__(16) ushort_t sB[128 * 32];
  const int tid = threadIdx.x;
  const int lane = tid & 63, wid = tid >> 6;
  const int lm = lane & 15, q = lane >> 4;
  const int wm = wid >> 1, wn = wid & 1;
  const long row0 = (long)blockIdx.x * 128;
  const long col0 = (long)blockIdx.y * 128;

  floatx4 acc[4][4] = {};

  const int srow = wid * 32 + (lane >> 2);
  const int skoff = (lane & 3) * 8;
  const ushort_t* Ag0 = A + (row0 + srow) * (long)K + skoff;
  const ushort_t* Ag1 = Ag0 + 16L * K;
  const ushort_t* Bg0 = Bt + (col0 + srow) * (long)K + skoff;
  const ushort_t* Bg1 = Bg0 + 16L * K;
  ushort_t* sA0 = sA + wid * 1024;
  ushort_t* sB0 = sB + wid * 1024;

  for (int k0 = 0; k0 < K; k0 += 32) {
    g2l16(Ag0 + k0, sA0);
    g2l16(Ag1 + k0, sA0 + 512);
    g2l16(Bg0 + k0, sB0);
    g2l16(Bg1 + k0, sB0 + 512);
    __syncthreads();
    bf16x8 af[4], bfr[4];
#pragma unroll
    for (int i = 0; i < 4; i++)
      af[i] = *(const bf16x8*)(const void*)&sA[(wm * 64 + i * 16 + lm) * 32 + q * 8];
#pragma unroll
    for (int j = 0; j < 4; j++)
      bfr[j] = *(const bf16x8*)(const void*)&sB[(wn * 64 + j * 16 + lm) * 32 + q * 8];
#pragma unroll
    for (int i = 0; i < 4; i++)
#pragma unroll
      for (int j = 0; j < 4; j++)
        acc[i][j] = __builtin_amdgcn_mfma_f32_16x16x32_bf16(af[i], bfr[j], acc[i][j], 0, 0, 0);
    __syncthreads();
  }
#pragma unroll
  for (int i = 0; i < 4; i++) {
#pragma unroll
    for (int r = 0; r < 4; r++) {
      long row = row0 + wm * 64 + i * 16 + q * 4 + r;
#pragma unroll
      for (int j = 0; j < 4; j++) {
        long col = col0 + wn * 64 + j * 16 + lm;
        float v = acc[i][j][r];
        if (MODE == 0) {
          ((ushort_t*)Cout)[row * (long)ldc + col] = f2b(v);
        } else if (MODE == 2) {
          ((ushort_t*)Cout)[row * (long)ldc + col] = f2b(10.0f * fast_tanh(v * 0.1f));
        } else if (MODE == 1) {
          float rv = resf[row * DD + col];
          ((ushort_t*)Cout)[row * (long)ldc + col] = f2b(rv + ls[col] * v);
        } else {
          float rv = b2f(resb[row * DD + col]);
          ((float*)Cout)[row * (long)ldc + col] = rv + ls[col] * v;
        }
      }
    }
  }
}

// ---------------- workspace layout (bytes), peak ~124.9 MB ----------------
#define OFF_WINT   0L                          // 9,633,792
#define OFF_WOUTT  9633792L                    // 4,718,592
#define OFF_WDNT   14352384L                   // 393,216
#define OFF_WUPT   14745600L                   // 1,572,864
#define OFF_GT     16318464L                   // 4,194,304
#define OFF_X1     20512768L                   // 12,582,912
#define OFF_WRT    33095680L                   // 262,144
#define OFF_ALPHA  33357824L                   // 786,432
#define OFF_SSUM   34144256L                   // 48*64*64*4 = 786,432
#define OFF_ASUM   34930688L                   // 48*64*4    = 12,288
#define OFF_CARRY  34942976L                   // 786,432
#define OFF_XN     35729408L                   // 12,582,912 (alias x2n)
#define OFF_Y      48312320L                   // 25,165,824 (alias moe)
#define OFF_PROJ   73478144L                   // 51,380,224 (alias abig+lat)
#define OFF_ABIG   OFF_PROJ
#define OFF_LAT    (OFF_PROJ + 33554432L)
#define OFF_X2N    OFF_XN
#define OFF_MOE    OFF_Y
#define WS_NEEDED  124858368L

extern "C" void kernel_launch(void* const* d_in, const int* in_sizes, int n_in,
                              void* d_out, int out_size, void* d_ws, size_t ws_size,
                              hipStream_t stream) {
  const float* x     = (const float*)d_in[0];
  const float* rms1w = (const float*)d_in[1];
  const float* W_in  = (const float*)d_in[2];
  const float* dtb   = (const float*)d_in[3];
  const float* W_out = (const float*)d_in[4];
  const float* ls1   = (const float*)d_in[5];
  const float* rms2w = (const float*)d_in[6];
  const float* W_dn  = (const float*)d_in[7];
  const float* W_rtr = (const float*)d_in[8];
  const float* G     = (const float*)d_in[9];
  const float* W_up  = (const float*)d_in[10];
  const float* ls2   = (const float*)d_in[11];
  if (ws_size < (size_t)WS_NEEDED) return;

  char* ws = (char*)d_ws;
  ushort_t* W_inT  = (ushort_t*)(ws + OFF_WINT);
  ushort_t* W_outT = (ushort_t*)(ws + OFF_WOUTT);
  ushort_t* W_dnT  = (ushort_t*)(ws + OFF_WDNT);
  ushort_t* W_upT  = (ushort_t*)(ws + OFF_WUPT);
  ushort_t* GT     = (ushort_t*)(ws + OFF_GT);
  ushort_t* x1     = (ushort_t*)(ws + OFF_X1);
  float*    wrt    = (float*)(ws + OFF_WRT);
  float*    alpha  = (float*)(ws + OFF_ALPHA);
  float*    ssum   = (float*)(ws + OFF_SSUM);
  float*    asum   = (float*)(ws + OFF_ASUM);
  float*    carry  = (float*)(ws + OFF_CARRY);
  ushort_t* xn     = (ushort_t*)(ws + OFF_XN);
  ushort_t* y      = (ushort_t*)(ws + OFF_Y);
  ushort_t* proj   = (ushort_t*)(ws + OFF_PROJ);
  ushort_t* abig   = (ushort_t*)(ws + OFF_ABIG);
  ushort_t* lat    = (ushort_t*)(ws + OFF_LAT);
  ushort_t* x2n    = (ushort_t*)(ws + OFF_X2N);
  ushort_t* moe    = (ushort_t*)(ws + OFF_MOE);
  float*    outp   = (float*)d_out;

  // weight transposes (f32 -> bf16), [K][N] -> [N][K]; W_in cols padded 6192->6272 w/ zeros
  k_tr<<<dim3(12, 98), 256, 0, stream>>>(W_in, W_inT, 768, 6192);
  k_tr<<<dim3(48, 12), 256, 0, stream>>>(W_out, W_outT, 3072, 768);
  k_tr<<<dim3(12, 4), 256, 0, stream>>>(W_dn, W_dnT, 768, 256);
  k_tr<<<dim3(16, 12), 256, 0, stream>>>(W_up, W_upT, 1024, 768);
  k_tr<<<dim3(32, 16), 256, 0, stream>>>(G, GT, 2048, 1024);

  k_rms<<<8192, 256, 0, stream>>>(x, rms1w, xn);

  for (int b = 0; b < 2; b++) {
    const ushort_t* xnb = xn + (long)b * LB * DD;
    k_gemm<0><<<dim3(32, 49), 256, 0, stream>>>(xnb, W_inT, proj, 768, (int)NP,
                                                nullptr, nullptr, nullptr);
    k_alpha<<<768, 256, 0, stream>>>(proj, dtb, alpha);
    k_scan1<<<3072, 64, 0, stream>>>(proj, alpha, ssum, asum);
    k_scan2<<<48, 64, 0, stream>>>(ssum, asum, carry);
    k_scan3<<<3072, 64, 0, stream>>>(proj, alpha, carry, y);
    k_gemm<1><<<dim3(32, 6), 256, 0, stream>>>(y, W_outT, x1 + (long)b * LB * DD, 3072, 768,
                                               x + (long)b * LB * DD, nullptr, ls1);
  }

  k_rms2_router<<<8192, 256, 0, stream>>>(x1, rms2w, W_rtr, x2n, wrt);
  k_gemm<2><<<dim3(64, 2), 256, 0, stream>>>(x2n, W_dnT, lat, 768, 256,
                                             nullptr, nullptr, nullptr);
  k_abig<<<16384, 256, 0, stream>>>(lat, wrt, abig);
  k_gemm<0><<<dim3(64, 8), 256, 0, stream>>>(abig, GT, moe, 2048, 1024,
                                             nullptr, nullptr, nullptr);
  k_gemm<3><<<dim3(64, 6), 256, 0, stream>>>(moe, W_upT, outp, 1024, 768,
                                             nullptr, x1, ls2);
}

// Round 5
// 575.779 us; speedup vs baseline: 1.2325x; 1.0511x over previous
//
#include <hip/hip_runtime.h>
#include <stdint.h>

typedef unsigned short ushort_t;
typedef __attribute__((ext_vector_type(8))) __bf16 bf16x8;
typedef __attribute__((ext_vector_type(4))) float floatx4;
typedef __attribute__((ext_vector_type(4))) unsigned short ushort4v;
typedef __attribute__((ext_vector_type(8))) unsigned short ushort8v;

// ---------------- constants ----------------
#define TT 8192L   // tokens = B*L
#define LB 4096L   // tokens per batch
#define DD 768L
#define DI 3072L
#define NH 48L
#define R3C 256L
#define R2C 1024L
#define NP 6272L   // padded proj width (2*DI + NH = 6192 -> 49*128)
#define CHS 64L    // scan chunk length (tokens)

// ---------------- helpers ----------------
__device__ __forceinline__ float b2f(ushort_t u) {
  union { unsigned u32; float f; } v; v.u32 = ((unsigned)u) << 16; return v.f;
}
__device__ __forceinline__ ushort_t f2b(float f) {
  union { float f; unsigned u32; } v; v.f = f;
  unsigned r = v.u32 + 0x7FFFu + ((v.u32 >> 16) & 1u);
  return (ushort_t)(r >> 16);
}
__device__ __forceinline__ float fast_tanh(float x) {
  float e = __expf(2.0f * x);
  return 1.0f - 2.0f / (e + 1.0f);
}
// async global->LDS, 16B/lane; LDS base wave-uniform. Only in 4-wave k_gemm.
__device__ __forceinline__ void g2l16(const void* g, void* l) {
  __builtin_amdgcn_global_load_lds(
      (const __attribute__((address_space(1))) unsigned int*)g,
      (__attribute__((address_space(3))) unsigned int*)l, 16, 0, 0);
}

// ---------------- transpose f32 -> bf16: dst[n][k] = src[k][n], zero-pad n>=N ----------------
__global__ __launch_bounds__(256) void k_tr(const float* __restrict__ src,
                                            ushort_t* __restrict__ dst,
                                            int K, int N) {
  __shared__ float tile[64][65];
  int k0 = blockIdx.x * 64, n0 = blockIdx.y * 64;
  int c = threadIdx.x & 63, r4 = threadIdx.x >> 6;
#pragma unroll
  for (int s = 0; s < 16; s++) {
    int r = s * 4 + r4;
    int n = n0 + c;
    tile[c][r] = (n < N) ? src[(long)(k0 + r) * N + n] : 0.0f;
  }
  __syncthreads();
#pragma unroll
  for (int s = 0; s < 16; s++) {
    int r = s * 4 + r4;
    dst[(long)(n0 + r) * K + k0 + c] = f2b(tile[r][c]);
  }
}

// ---------------- RMSNorm: f32 in -> bf16 out ----------------
__global__ __launch_bounds__(256) void k_rms(const float* __restrict__ x,
                                             const float* __restrict__ w,
                                             ushort_t* __restrict__ out) {
  int t = blockIdx.x, tid = threadIdx.x;
  int lane = tid & 63, wid = tid >> 6;
  const float* xr = x + (long)t * DD;
  float v0 = xr[tid], v1 = xr[tid + 256], v2 = xr[tid + 512];
  float ss = v0 * v0 + v1 * v1 + v2 * v2;
  for (int o = 32; o; o >>= 1) ss += __shfl_down(ss, o);
  __shared__ float red[4];
  if (lane == 0) red[wid] = ss;
  __syncthreads();
  float tot = red[0] + red[1] + red[2] + red[3];
  float rr = rsqrtf(tot / 768.0f + 1e-5f);
  ushort_t* orow = out + (long)t * DD;
  orow[tid]       = f2b(v0 * rr * w[tid]);
  orow[tid + 256] = f2b(v1 * rr * w[tid + 256]);
  orow[tid + 512] = f2b(v2 * rr * w[tid + 512]);
}

// ---------------- RMSNorm2 (bf16 x1) + router (f32 W_router [768][8]) ----------------
__global__ __launch_bounds__(256) void k_rms2_router(const ushort_t* __restrict__ x1,
                                                     const float* __restrict__ w,
                                                     const float* __restrict__ wr,
                                                     ushort_t* __restrict__ x2n,
                                                     float* __restrict__ wrt) {
  int t = blockIdx.x, tid = threadIdx.x;
  int lane = tid & 63, wid = tid >> 6;
  const ushort_t* xr = x1 + (long)t * DD;
  float v[3];
  int dd[3] = {tid, tid + 256, tid + 512};
  v[0] = b2f(xr[dd[0]]); v[1] = b2f(xr[dd[1]]); v[2] = b2f(xr[dd[2]]);
  float ss = v[0] * v[0] + v[1] * v[1] + v[2] * v[2];
  for (int o = 32; o; o >>= 1) ss += __shfl_down(ss, o);
  __shared__ float red[4];
  __shared__ float wred[4][8];
  __shared__ float slog[8];
  if (lane == 0) red[wid] = ss;
  __syncthreads();
  float tot = red[0] + red[1] + red[2] + red[3];
  float rr = rsqrtf(tot / 768.0f + 1e-5f);
  float p[8] = {0, 0, 0, 0, 0, 0, 0, 0};
  ushort_t* orow = x2n + (long)t * DD;
#pragma unroll
  for (int i = 0; i < 3; i++) {
    float xnv = v[i] * rr * w[dd[i]];
    orow[dd[i]] = f2b(xnv);
    const float* wrow = wr + (long)dd[i] * 8;
#pragma unroll
    for (int e = 0; e < 8; e++) p[e] += xnv * wrow[e];
  }
#pragma unroll
  for (int e = 0; e < 8; e++) {
    float s = p[e];
    for (int o = 32; o; o >>= 1) s += __shfl_down(s, o);
    if (lane == 0) wred[wid][e] = s;
  }
  __syncthreads();
  if (tid < 8)
    slog[tid] = (wred[0][tid] + wred[1][tid] + wred[2][tid] + wred[3][tid]) * 2.0f;
  __syncthreads();
  if (tid == 0) {
    float l[8];
#pragma unroll
    for (int e = 0; e < 8; e++) l[e] = slog[e];
    int e0 = 0; float b0 = l[0];
#pragma unroll
    for (int e = 1; e < 8; e++) if (l[e] > b0) { b0 = l[e]; e0 = e; }
    int e1 = -1; float b1 = -1e30f;
#pragma unroll
    for (int e = 0; e < 8; e++) if (e != e0 && l[e] > b1) { b1 = l[e]; e1 = e; }
    float ex = __expf(b1 - b0);
    float pd = 1.0f / (1.0f + ex);
    float* wo = wrt + (long)t * 8;
#pragma unroll
    for (int e = 0; e < 8; e++) wo[e] = 0.0f;
    wo[e0] = pd;
    wo[e1] = ex * pd;
  }
}

// ---------------- alpha = exp(-softplus(dt + bias)); batch-local [h][t] ----------------
__global__ __launch_bounds__(256) void k_alpha(const ushort_t* __restrict__ proj,
                                               const float* __restrict__ dtb,
                                               float* __restrict__ alpha) {
  int gid = blockIdx.x * 256 + threadIdx.x;   // < 196608 = 4096*48
  int tg = gid / 48;
  int h = gid - tg * 48;
  float dt = b2f(proj[(long)tg * NP + 2 * DI + h]) + dtb[h];
  float sp = (dt > 20.0f) ? dt : log1pf(__expf(dt));
  alpha[(long)h * LB + tg] = __expf(-sp);
}

// stage one 64-token x 64-dim head-slice tile into LDS via registers.
// lds[tt*64 + dim] == src[tt][dim]
__device__ __forceinline__ void stage_tile(const ushort_t* __restrict__ g, long rowstride,
                                           ushort_t* __restrict__ lds, int lane) {
  const int lrow = lane >> 3;
  const int dcol = (lane & 7) * 8;
#pragma unroll
  for (int c8 = 0; c8 < 8; c8++) {
    ushort8v v = *(const ushort8v*)(g + (long)(c8 * 8 + lrow) * rowstride + dcol);
    *(ushort8v*)&lds[(c8 * 64 + lane) * 8] = v;
  }
}

// ---------------- scan phase 1: per-chunk (64-token) summaries, 3072 blocks ----------------
__global__ __launch_bounds__(64) void k_scan1(const ushort_t* __restrict__ proj,
                                              const float* __restrict__ alpha,
                                              float* __restrict__ ssum,
                                              float* __restrict__ asum) {
  __shared__ __align__(16) ushort_t u_lds[64 * 64];
  __shared__ float s_alpha[64];
  const int lane = threadIdx.x;
  const int idx = blockIdx.x;          // h*64 + c
  const int c = idx & 63;
  const int h = idx >> 6;
  s_alpha[lane] = alpha[(long)h * LB + (long)c * CHS + lane];
  const ushort_t* ug = proj + (long)c * CHS * NP + (long)h * 64;
  stage_tile(ug, NP, u_lds, lane);
  __syncthreads();
  float s = 0.0f, A = 1.0f;
#pragma unroll
  for (int tt = 0; tt < 64; tt++) {
    float a = s_alpha[tt];
    float u = b2f(u_lds[tt * 64 + lane]);
    s = fmaf(a, s, u);
    A *= a;
  }
  ssum[(long)idx * 64 + lane] = s;
  if (lane == 0) asum[idx] = A;
}

// ---------------- scan phase 2: chunk carries (48 blocks, 64-step serial) ----------------
__global__ __launch_bounds__(64) void k_scan2(const float* __restrict__ ssum,
                                              const float* __restrict__ asum,
                                              float* __restrict__ carry) {
  int h = blockIdx.x, lane = threadIdx.x;
  float cv = 0.0f;
  for (int c = 0; c < 64; c++) {
    carry[((long)h * 64 + c) * 64 + lane] = cv;
    float A = asum[h * 64 + c];
    float s = ssum[((long)h * 64 + c) * 64 + lane];
    cv = A * cv + s;
  }
}

// ---------------- scan phase 3: scan + silu gate + scaled tanh, 3072 blocks ----------------
__global__ __launch_bounds__(64) void k_scan3(const ushort_t* __restrict__ proj,
                                              const float* __restrict__ alpha,
                                              const float* __restrict__ carry,
                                              ushort_t* __restrict__ y) {
  __shared__ __align__(16) ushort_t u_lds[64 * 64];
  __shared__ __align__(16) ushort_t z_lds[64 * 64];
  __shared__ float s_alpha[64];
  const int lane = threadIdx.x;
  const int idx = blockIdx.x;          // h*64 + c
  const int c = idx & 63;
  const int h = idx >> 6;
  s_alpha[lane] = alpha[(long)h * LB + (long)c * CHS + lane];
  const ushort_t* ug = proj + (long)c * CHS * NP + (long)h * 64;
  const ushort_t* zg = ug + DI;
  ushort_t* yg = y + (long)c * CHS * DI + (long)h * 64;
  stage_tile(ug, NP, u_lds, lane);
  stage_tile(zg, NP, z_lds, lane);
  __syncthreads();
  float hs = carry[(long)idx * 64 + lane];
#pragma unroll
  for (int tt = 0; tt < 64; tt++) {
    float a = s_alpha[tt];
    float u = b2f(u_lds[tt * 64 + lane]);
    hs = fmaf(a, hs, u);
    float zv = b2f(z_lds[tt * 64 + lane]);
    float sig = 1.0f / (1.0f + __expf(-zv));
    float yv = hs * zv * sig;
    yv = 10.0f * fast_tanh(yv * 0.1f);
    yg[(long)tt * DI + lane] = f2b(yv);
  }
}

// ---------------- A_big[t][e*256+r] = w[t][e]*lat[t][r] ----------------
__global__ __launch_bounds__(256) void k_abig(const ushort_t* __restrict__ lat,
                                              const float* __restrict__ wrt,
                                              ushort_t* __restrict__ abig) {
  long gid = (long)blockIdx.x * 256 + threadIdx.x;
  long idx = gid * 4;
  int t = (int)(idx >> 11);
  int off = (int)(idx & 2047);
  int e = off >> 8, r = off & 255;
  float wv = wrt[(long)t * 8 + e];
  ushort4v lv = *(const ushort4v*)(lat + (long)t * R3C + r);
  ushort4v ov;
  ov.x = f2b(wv * b2f(lv.x));
  ov.y = f2b(wv * b2f(lv.y));
  ov.z = f2b(wv * b2f(lv.z));
  ov.w = f2b(wv * b2f(lv.w));
  *(ushort4v*)(abig + (long)t * 2048 + off) = ov;
}

// ---------------- bf16 GEMM, B^T input (m97 structure), optional K-split ----------------
// MODE 0: bf16 C = A@B      MODE 4: f32 partial C[z] = A@B over K-slice z
// K = per-split K length; kstride = full row stride of A/Bt; zoff = partial buf stride.
template <int MODE>
__global__ __launch_bounds__(256, 4) void k_gemm(const ushort_t* __restrict__ A,   // [M][kstride]
                                                 const ushort_t* __restrict__ Bt,  // [N][kstride]
                                                 void* __restrict__ Cout, int K, int kstride,
                                                 int ldc, long zoff) {
  __shared__ __align__(16) ushort_t sA[128 * 32];
  __shared__ __align__(16) ushort_t sB[128 * 32];
  const int tid = threadIdx.x;
  const int lane = tid & 63, wid = tid >> 6;
  const int lm = lane & 15, q = lane >> 4;
  const int wm = wid >> 1, wn = wid & 1;
  const long row0 = (long)blockIdx.x * 128;
  const long col0 = (long)blockIdx.y * 128;
  const int z = blockIdx.z;
  A += (long)z * K;
  Bt += (long)z * K;

  floatx4 acc[4][4] = {};

  const int srow = wid * 32 + (lane >> 2);
  const int skoff = (lane & 3) * 8;
  const ushort_t* Ag0 = A + (row0 + srow) * (long)kstride + skoff;
  const ushort_t* Ag1 = Ag0 + 16L * kstride;
  const ushort_t* Bg0 = Bt + (col0 + srow) * (long)kstride + skoff;
  const ushort_t* Bg1 = Bg0 + 16L * kstride;
  ushort_t* sA0 = sA + wid * 1024;
  ushort_t* sB0 = sB + wid * 1024;

  for (int k0 = 0; k0 < K; k0 += 32) {
    g2l16(Ag0 + k0, sA0);
    g2l16(Ag1 + k0, sA0 + 512);
    g2l16(Bg0 + k0, sB0);
    g2l16(Bg1 + k0, sB0 + 512);
    __syncthreads();
    bf16x8 af[4], bfr[4];
#pragma unroll
    for (int i = 0; i < 4; i++)
      af[i] = *(const bf16x8*)(const void*)&sA[(wm * 64 + i * 16 + lm) * 32 + q * 8];
#pragma unroll
    for (int j = 0; j < 4; j++)
      bfr[j] = *(const bf16x8*)(const void*)&sB[(wn * 64 + j * 16 + lm) * 32 + q * 8];
#pragma unroll
    for (int i = 0; i < 4; i++)
#pragma unroll
      for (int j = 0; j < 4; j++)
        acc[i][j] = __builtin_amdgcn_mfma_f32_16x16x32_bf16(af[i], bfr[j], acc[i][j], 0, 0, 0);
    __syncthreads();
  }
#pragma unroll
  for (int i = 0; i < 4; i++) {
#pragma unroll
    for (int r = 0; r < 4; r++) {
      long row = row0 + wm * 64 + i * 16 + q * 4 + r;
#pragma unroll
      for (int j = 0; j < 4; j++) {
        long col = col0 + wn * 64 + j * 16 + lm;
        float v = acc[i][j][r];
        if (MODE == 0) {
          ((ushort_t*)Cout)[row * (long)ldc + col] = f2b(v);
        } else {
          ((float*)Cout)[(long)z * zoff + row * (long)ldc + col] = v;
        }
      }
    }
  }
}

// ---------------- split-K combine kernels (float4-vectorized, no tails) ----------------
// x1 = f2b(x + ls * sum_z P)     (out-proj epilogue)
__global__ __launch_bounds__(256) void k_comb_res(const float* __restrict__ P, long zoff, int nz,
                                                  const float* __restrict__ x,
                                                  const float* __restrict__ ls,
                                                  ushort_t* __restrict__ x1) {
  long i = ((long)blockIdx.x * 256 + threadIdx.x) * 4;
  float s[4] = {0, 0, 0, 0};
  for (int zz = 0; zz < nz; zz++) {
    const float* p = P + (long)zz * zoff + i;
#pragma unroll
    for (int j = 0; j < 4; j++) s[j] += p[j];
  }
  int c = (int)(i % DD);
#pragma unroll
  for (int j = 0; j < 4; j++) x1[i + j] = f2b(x[i + j] + ls[c + j] * s[j]);
}

// lat = f2b(10*tanh(0.1 * sum_z P))   (down-proj epilogue)
__global__ __launch_bounds__(256) void k_comb_tanh(const float* __restrict__ P, long zoff, int nz,
                                                   ushort_t* __restrict__ lat) {
  long i = ((long)blockIdx.x * 256 + threadIdx.x) * 4;
  float s[4] = {0, 0, 0, 0};
  for (int zz = 0; zz < nz; zz++) {
    const float* p = P + (long)zz * zoff + i;
#pragma unroll
    for (int j = 0; j < 4; j++) s[j] += p[j];
  }
#pragma unroll
  for (int j = 0; j < 4; j++) lat[i + j] = f2b(10.0f * fast_tanh(0.1f * s[j]));
}

// out(f32) = b2f(x1) + ls2 * sum_z P   (up-proj epilogue)
__global__ __launch_bounds__(256) void k_comb_out(const float* __restrict__ P, long zoff, int nz,
                                                  const ushort_t* __restrict__ x1,
                                                  const float* __restrict__ ls,
                                                  float* __restrict__ outp) {
  long i = ((long)blockIdx.x * 256 + threadIdx.x) * 4;
  float s[4] = {0, 0, 0, 0};
  for (int zz = 0; zz < nz; zz++) {
    const float* p = P + (long)zz * zoff + i;
#pragma unroll
    for (int j = 0; j < 4; j++) s[j] += p[j];
  }
  int c = (int)(i % DD);
#pragma unroll
  for (int j = 0; j < 4; j++) outp[i + j] = b2f(x1[i + j]) + ls[c + j] * s[j];
}

// ---------------- workspace layout (bytes), peak ~124.9 MB ----------------
#define OFF_WINT   0L                          // 9,633,792
#define OFF_WOUTT  9633792L                    // 4,718,592
#define OFF_WDNT   14352384L                   // 393,216
#define OFF_WUPT   14745600L                   // 1,572,864
#define OFF_GT     16318464L                   // 4,194,304
#define OFF_X1     20512768L                   // 12,582,912
#define OFF_WRT    33095680L                   // 262,144
#define OFF_ALPHA  33357824L                   // 786,432
#define OFF_SSUM   34144256L                   // 786,432
#define OFF_ASUM   34930688L                   // 12,288
#define OFF_CARRY  34942976L                   // 786,432
#define OFF_XN     35729408L                   // 12,582,912 (alias x2n)
#define OFF_Y      48312320L                   // 25,165,824 (alias moe)
#define OFF_PROJ   73478144L                   // 51,380,224 (alias abig+lat, split-K partials)
#define OFF_ABIG   OFF_PROJ
#define OFF_LAT    (OFF_PROJ + 33554432L)
#define OFF_PART   OFF_PROJ                    // split-K partials (<= 50.3 MB, proj dead)
#define OFF_X2N    OFF_XN
#define OFF_MOE    OFF_Y
#define WS_NEEDED  124858368L

extern "C" void kernel_launch(void* const* d_in, const int* in_sizes, int n_in,
                              void* d_out, int out_size, void* d_ws, size_t ws_size,
                              hipStream_t stream) {
  const float* x     = (const float*)d_in[0];
  const float* rms1w = (const float*)d_in[1];
  const float* W_in  = (const float*)d_in[2];
  const float* dtb   = (const float*)d_in[3];
  const float* W_out = (const float*)d_in[4];
  const float* ls1   = (const float*)d_in[5];
  const float* rms2w = (const float*)d_in[6];
  const float* W_dn  = (const float*)d_in[7];
  const float* W_rtr = (const float*)d_in[8];
  const float* G     = (const float*)d_in[9];
  const float* W_up  = (const float*)d_in[10];
  const float* ls2   = (const float*)d_in[11];
  if (ws_size < (size_t)WS_NEEDED) return;

  char* ws = (char*)d_ws;
  ushort_t* W_inT  = (ushort_t*)(ws + OFF_WINT);
  ushort_t* W_outT = (ushort_t*)(ws + OFF_WOUTT);
  ushort_t* W_dnT  = (ushort_t*)(ws + OFF_WDNT);
  ushort_t* W_upT  = (ushort_t*)(ws + OFF_WUPT);
  ushort_t* GT     = (ushort_t*)(ws + OFF_GT);
  ushort_t* x1     = (ushort_t*)(ws + OFF_X1);
  float*    wrt    = (float*)(ws + OFF_WRT);
  float*    alpha  = (float*)(ws + OFF_ALPHA);
  float*    ssum   = (float*)(ws + OFF_SSUM);
  float*    asum   = (float*)(ws + OFF_ASUM);
  float*    carry  = (float*)(ws + OFF_CARRY);
  ushort_t* xn     = (ushort_t*)(ws + OFF_XN);
  ushort_t* y      = (ushort_t*)(ws + OFF_Y);
  ushort_t* proj   = (ushort_t*)(ws + OFF_PROJ);
  ushort_t* abig   = (ushort_t*)(ws + OFF_ABIG);
  ushort_t* lat    = (ushort_t*)(ws + OFF_LAT);
  float*    part   = (float*)(ws + OFF_PART);
  ushort_t* x2n    = (ushort_t*)(ws + OFF_X2N);
  ushort_t* moe    = (ushort_t*)(ws + OFF_MOE);
  float*    outp   = (float*)d_out;

  // weight transposes (f32 -> bf16), [K][N] -> [N][K]; W_in cols padded 6192->6272 w/ zeros
  k_tr<<<dim3(12, 98), 256, 0, stream>>>(W_in, W_inT, 768, 6192);
  k_tr<<<dim3(48, 12), 256, 0, stream>>>(W_out, W_outT, 3072, 768);
  k_tr<<<dim3(12, 4), 256, 0, stream>>>(W_dn, W_dnT, 768, 256);
  k_tr<<<dim3(16, 12), 256, 0, stream>>>(W_up, W_upT, 1024, 768);
  k_tr<<<dim3(32, 16), 256, 0, stream>>>(G, GT, 2048, 1024);

  k_rms<<<8192, 256, 0, stream>>>(x, rms1w, xn);

  for (int b = 0; b < 2; b++) {
    const ushort_t* xnb = xn + (long)b * LB * DD;
    // in-proj: M=4096, N=6272, K=768 (1568 blocks)
    k_gemm<0><<<dim3(32, 49, 1), 256, 0, stream>>>(xnb, W_inT, proj, 768, 768, (int)NP, 0);
    k_alpha<<<768, 256, 0, stream>>>(proj, dtb, alpha);
    k_scan1<<<3072, 64, 0, stream>>>(proj, alpha, ssum, asum);
    k_scan2<<<48, 64, 0, stream>>>(ssum, asum, carry);
    k_scan3<<<3072, 64, 0, stream>>>(proj, alpha, carry, y);
    // out-proj split-K z=4: M=4096, N=768, K=3072 -> 768 blocks (proj dead, partials alias it)
    k_gemm<4><<<dim3(32, 6, 4), 256, 0, stream>>>(y, W_outT, part, 768, 3072, 768, LB * DD);
    k_comb_res<<<3072, 256, 0, stream>>>(part, LB * DD, 4, x + (long)b * LB * DD, ls1,
                                         x1 + (long)b * LB * DD);
  }

  k_rms2_router<<<8192, 256, 0, stream>>>(x1, rms2w, W_rtr, x2n, wrt);
  // down-proj split-K z=3: M=8192, N=256, K=768 -> 384 blocks
  k_gemm<4><<<dim3(64, 2, 3), 256, 0, stream>>>(x2n, W_dnT, part, 256, 768, 256, TT * R3C);
  k_comb_tanh<<<2048, 256, 0, stream>>>(part, TT * R3C, 3, lat);
  k_abig<<<16384, 256, 0, stream>>>(lat, wrt, abig);
  // MoE: M=8192, N=1024, K=2048 (512 blocks)
  k_gemm<0><<<dim3(64, 8, 1), 256, 0, stream>>>(abig, GT, moe, 2048, 2048, 1024, 0);
  // up-proj split-K z=2: M=8192, N=768, K=1024 -> 768 blocks (abig/lat dead)
  k_gemm<4><<<dim3(64, 6, 2), 256, 0, stream>>>(moe, W_upT, part, 512, 1024, 768, TT * DD);
  k_comb_out<<<6144, 256, 0, stream>>>(part, TT * DD, 2, x1, ls2, outp);
}

// Round 6
// 519.003 us; speedup vs baseline: 1.3673x; 1.1094x over previous
//
#include <hip/hip_runtime.h>
#include <stdint.h>

typedef unsigned short ushort_t;
typedef __attribute__((ext_vector_type(8))) __bf16 bf16x8;
typedef __attribute__((ext_vector_type(4))) float floatx4;
typedef __attribute__((ext_vector_type(4))) unsigned short ushort4v;
typedef __attribute__((ext_vector_type(8))) unsigned short ushort8v;

// ---------------- constants ----------------
#define TT 8192L   // tokens = B*L
#define LB 4096L   // tokens per batch
#define DD 768L
#define DI 3072L
#define NH 48L
#define R3C 256L
#define R2C 1024L
#define NP 6272L   // padded proj width (2*DI + NH = 6192 -> 49*128)
#define CHS 64L    // scan chunk length (tokens)

// ---------------- helpers ----------------
__device__ __forceinline__ float b2f(ushort_t u) {
  union { unsigned u32; float f; } v; v.u32 = ((unsigned)u) << 16; return v.f;
}
__device__ __forceinline__ ushort_t f2b(float f) {
  union { float f; unsigned u32; } v; v.f = f;
  unsigned r = v.u32 + 0x7FFFu + ((v.u32 >> 16) & 1u);
  return (ushort_t)(r >> 16);
}
__device__ __forceinline__ float fast_tanh(float x) {
  float e = __expf(2.0f * x);
  return 1.0f - 2.0f / (e + 1.0f);
}
// async global->LDS, 16B/lane; LDS base wave-uniform. Only in 4-wave k_gemm.
__device__ __forceinline__ void g2l16(const void* g, void* l) {
  __builtin_amdgcn_global_load_lds(
      (const __attribute__((address_space(1))) unsigned int*)g,
      (__attribute__((address_space(3))) unsigned int*)l, 16, 0, 0);
}

// ---------------- merged transpose f32 -> bf16: dst[n][k] = src[k][n], zero-pad ----------------
// 5 matrices hard-coded: W_in(768x6192,g12x98) W_out(3072x768,g48x12) W_dn(768x256,g12x4)
//                        W_up(1024x768,g16x12) G(2048x1024,g32x16); total 2504 blocks
__global__ __launch_bounds__(256) void k_tr_all(const float* __restrict__ s0, ushort_t* __restrict__ d0,
                                                const float* __restrict__ s1, ushort_t* __restrict__ d1,
                                                const float* __restrict__ s2, ushort_t* __restrict__ d2,
                                                const float* __restrict__ s3, ushort_t* __restrict__ d3,
                                                const float* __restrict__ s4, ushort_t* __restrict__ d4) {
  __shared__ float tile[64][65];
  int id = blockIdx.x;
  const float* src; ushort_t* dst; int K, N, gx;
  if (id < 1176)      {            src = s0; dst = d0; K = 768;  N = 6192; gx = 12; }
  else if (id < 1752) { id -= 1176; src = s1; dst = d1; K = 3072; N = 768;  gx = 48; }
  else if (id < 1800) { id -= 1752; src = s2; dst = d2; K = 768;  N = 256;  gx = 12; }
  else if (id < 1992) { id -= 1800; src = s3; dst = d3; K = 1024; N = 768;  gx = 16; }
  else                { id -= 1992; src = s4; dst = d4; K = 2048; N = 1024; gx = 32; }
  int k0 = (id % gx) * 64, n0 = (id / gx) * 64;
  int c = threadIdx.x & 63, r4 = threadIdx.x >> 6;
#pragma unroll
  for (int s = 0; s < 16; s++) {
    int r = s * 4 + r4;
    int n = n0 + c;
    tile[c][r] = (n < N) ? src[(long)(k0 + r) * N + n] : 0.0f;
  }
  __syncthreads();
#pragma unroll
  for (int s = 0; s < 16; s++) {
    int r = s * 4 + r4;
    dst[(long)(n0 + r) * K + k0 + c] = f2b(tile[r][c]);
  }
}

// ---------------- RMSNorm: f32 in -> bf16 out ----------------
__global__ __launch_bounds__(256) void k_rms(const float* __restrict__ x,
                                             const float* __restrict__ w,
                                             ushort_t* __restrict__ out) {
  int t = blockIdx.x, tid = threadIdx.x;
  int lane = tid & 63, wid = tid >> 6;
  const float* xr = x + (long)t * DD;
  float v0 = xr[tid], v1 = xr[tid + 256], v2 = xr[tid + 512];
  float ss = v0 * v0 + v1 * v1 + v2 * v2;
  for (int o = 32; o; o >>= 1) ss += __shfl_down(ss, o);
  __shared__ float red[4];
  if (lane == 0) red[wid] = ss;
  __syncthreads();
  float tot = red[0] + red[1] + red[2] + red[3];
  float rr = rsqrtf(tot / 768.0f + 1e-5f);
  ushort_t* orow = out + (long)t * DD;
  orow[tid]       = f2b(v0 * rr * w[tid]);
  orow[tid + 256] = f2b(v1 * rr * w[tid + 256]);
  orow[tid + 512] = f2b(v2 * rr * w[tid + 512]);
}

// ---------------- fused out-proj combine + RMSNorm2 + router (per batch, 4096 blocks) ----------
// x1 = x + ls1*sum_z P (f32, stored bf16); x2n = rmsnorm(x1)*w2 (bf16); wrt = top2-softmax router
__global__ __launch_bounds__(256) void k_fuse2(const float* __restrict__ P,   // [4][LB*DD]
                                               const float* __restrict__ x,   // batch offset
                                               const float* __restrict__ ls1,
                                               const float* __restrict__ w2,
                                               const float* __restrict__ wr,  // [768][8]
                                               ushort_t* __restrict__ x1,
                                               ushort_t* __restrict__ x2n,
                                               float* __restrict__ wrt) {
  int t = blockIdx.x, tid = threadIdx.x;
  int lane = tid & 63, wid = tid >> 6;
  int dd[3] = {tid, tid + 256, tid + 512};
  float v[3];
#pragma unroll
  for (int i = 0; i < 3; i++) {
    long ix = (long)t * DD + dd[i];
    float s = P[ix] + P[LB * DD + ix] + P[2 * LB * DD + ix] + P[3 * LB * DD + ix];
    float xv = x[ix] + ls1[dd[i]] * s;
    x1[ix] = f2b(xv);
    v[i] = xv;
  }
  float ss = v[0] * v[0] + v[1] * v[1] + v[2] * v[2];
  for (int o = 32; o; o >>= 1) ss += __shfl_down(ss, o);
  __shared__ float red[4];
  __shared__ float wred[4][8];
  __shared__ float slog[8];
  if (lane == 0) red[wid] = ss;
  __syncthreads();
  float tot = red[0] + red[1] + red[2] + red[3];
  float rr = rsqrtf(tot / 768.0f + 1e-5f);
  float p[8] = {0, 0, 0, 0, 0, 0, 0, 0};
  ushort_t* orow = x2n + (long)t * DD;
#pragma unroll
  for (int i = 0; i < 3; i++) {
    float xnv = v[i] * rr * w2[dd[i]];
    orow[dd[i]] = f2b(xnv);
    const float* wrow = wr + (long)dd[i] * 8;
#pragma unroll
    for (int e = 0; e < 8; e++) p[e] += xnv * wrow[e];
  }
#pragma unroll
  for (int e = 0; e < 8; e++) {
    float s = p[e];
    for (int o = 32; o; o >>= 1) s += __shfl_down(s, o);
    if (lane == 0) wred[wid][e] = s;
  }
  __syncthreads();
  if (tid < 8)
    slog[tid] = (wred[0][tid] + wred[1][tid] + wred[2][tid] + wred[3][tid]) * 2.0f;
  __syncthreads();
  if (tid == 0) {
    float l[8];
#pragma unroll
    for (int e = 0; e < 8; e++) l[e] = slog[e];
    int e0 = 0; float b0 = l[0];
#pragma unroll
    for (int e = 1; e < 8; e++) if (l[e] > b0) { b0 = l[e]; e0 = e; }
    int e1 = -1; float b1 = -1e30f;
#pragma unroll
    for (int e = 0; e < 8; e++) if (e != e0 && l[e] > b1) { b1 = l[e]; e1 = e; }
    float ex = __expf(b1 - b0);
    float pd = 1.0f / (1.0f + ex);
    float* wo = wrt + (long)t * 8;
#pragma unroll
    for (int e = 0; e < 8; e++) wo[e] = 0.0f;
    wo[e0] = pd;
    wo[e1] = ex * pd;
  }
}

// stage one 64-token x 64-dim head-slice tile into LDS via registers.
// lds[tt*64 + dim] == src[tt][dim]
__device__ __forceinline__ void stage_tile(const ushort_t* __restrict__ g, long rowstride,
                                           ushort_t* __restrict__ lds, int lane) {
  const int lrow = lane >> 3;
  const int dcol = (lane & 7) * 8;
#pragma unroll
  for (int c8 = 0; c8 < 8; c8++) {
    ushort8v v = *(const ushort8v*)(g + (long)(c8 * 8 + lrow) * rowstride + dcol);
    *(ushort8v*)&lds[(c8 * 64 + lane) * 8] = v;
  }
}

__device__ __forceinline__ float alpha_of(const ushort_t* __restrict__ proj, int tok, int h,
                                          const float* __restrict__ dtb) {
  float dt = b2f(proj[(long)tok * NP + 2 * DI + h]) + dtb[h];
  float sp = (dt > 20.0f) ? dt : log1pf(__expf(dt));
  return __expf(-sp);
}

// ---------------- scan phase 1: per-chunk (64-token) summaries, 3072 blocks ----------------
__global__ __launch_bounds__(64) void k_scan1(const ushort_t* __restrict__ proj,
                                              const float* __restrict__ dtb,
                                              float* __restrict__ ssum,
                                              float* __restrict__ asum) {
  __shared__ __align__(16) ushort_t u_lds[64 * 64];
  __shared__ float s_alpha[64];
  const int lane = threadIdx.x;
  const int idx = blockIdx.x;          // h*64 + c
  const int c = idx & 63;
  const int h = idx >> 6;
  s_alpha[lane] = alpha_of(proj, (int)(c * CHS) + lane, h, dtb);
  const ushort_t* ug = proj + (long)c * CHS * NP + (long)h * 64;
  stage_tile(ug, NP, u_lds, lane);
  __syncthreads();
  float s = 0.0f, A = 1.0f;
#pragma unroll
  for (int tt = 0; tt < 64; tt++) {
    float a = s_alpha[tt];
    float u = b2f(u_lds[tt * 64 + lane]);
    s = fmaf(a, s, u);
    A *= a;
  }
  ssum[(long)idx * 64 + lane] = s;
  if (lane == 0) asum[idx] = A;
}

// ---------------- scan phase 2: chunk carries (48 blocks, 64-step serial) ----------------
__global__ __launch_bounds__(64) void k_scan2(const float* __restrict__ ssum,
                                              const float* __restrict__ asum,
                                              float* __restrict__ carry) {
  int h = blockIdx.x, lane = threadIdx.x;
  float cv = 0.0f;
  for (int c = 0; c < 64; c++) {
    carry[((long)h * 64 + c) * 64 + lane] = cv;
    float A = asum[h * 64 + c];
    float s = ssum[((long)h * 64 + c) * 64 + lane];
    cv = A * cv + s;
  }
}

// ---------------- scan phase 3: scan + silu gate + scaled tanh, 3072 blocks ----------------
__global__ __launch_bounds__(64) void k_scan3(const ushort_t* __restrict__ proj,
                                              const float* __restrict__ dtb,
                                              const float* __restrict__ carry,
                                              ushort_t* __restrict__ y) {
  __shared__ __align__(16) ushort_t u_lds[64 * 64];
  __shared__ __align__(16) ushort_t z_lds[64 * 64];
  __shared__ float s_alpha[64];
  const int lane = threadIdx.x;
  const int idx = blockIdx.x;          // h*64 + c
  const int c = idx & 63;
  const int h = idx >> 6;
  s_alpha[lane] = alpha_of(proj, (int)(c * CHS) + lane, h, dtb);
  const ushort_t* ug = proj + (long)c * CHS * NP + (long)h * 64;
  const ushort_t* zg = ug + DI;
  ushort_t* yg = y + (long)c * CHS * DI + (long)h * 64;
  stage_tile(ug, NP, u_lds, lane);
  stage_tile(zg, NP, z_lds, lane);
  __syncthreads();
  float hs = carry[(long)idx * 64 + lane];
#pragma unroll
  for (int tt = 0; tt < 64; tt++) {
    float a = s_alpha[tt];
    float u = b2f(u_lds[tt * 64 + lane]);
    hs = fmaf(a, hs, u);
    float zv = b2f(z_lds[tt * 64 + lane]);
    float sig = 1.0f / (1.0f + __expf(-zv));
    float yv = hs * zv * sig;
    yv = 10.0f * fast_tanh(yv * 0.1f);
    yg[(long)tt * DI + lane] = f2b(yv);
  }
}

// ---------------- A_big[t][e*256+r] = w[t][e]*lat[t][r] ----------------
__global__ __launch_bounds__(256) void k_abig(const ushort_t* __restrict__ lat,
                                              const float* __restrict__ wrt,
                                              ushort_t* __restrict__ abig) {
  long gid = (long)blockIdx.x * 256 + threadIdx.x;
  long idx = gid * 4;
  int t = (int)(idx >> 11);
  int off = (int)(idx & 2047);
  int e = off >> 8, r = off & 255;
  float wv = wrt[(long)t * 8 + e];
  ushort4v lv = *(const ushort4v*)(lat + (long)t * R3C + r);
  ushort4v ov;
  ov.x = f2b(wv * b2f(lv.x));
  ov.y = f2b(wv * b2f(lv.y));
  ov.z = f2b(wv * b2f(lv.z));
  ov.w = f2b(wv * b2f(lv.w));
  *(ushort4v*)(abig + (long)t * 2048 + off) = ov;
}

// ---------------- bf16 GEMM, B^T input, BK=64 (two proven 128x32 panels per barrier) -------
// MODE 0: bf16 C = A@B      MODE 4: f32 partial C[z] = A@B over K-slice z
template <int MODE>
__global__ __launch_bounds__(256, 4) void k_gemm(const ushort_t* __restrict__ A,   // [M][kstride]
                                                 const ushort_t* __restrict__ Bt,  // [N][kstride]
                                                 void* __restrict__ Cout, int K, int kstride,
                                                 int ldc, long zoff) {
  __shared__ __align__(16) ushort_t sA[2 * 128 * 32];
  __shared__ __align__(16) ushort_t sB[2 * 128 * 32];
  const int tid = threadIdx.x;
  const int lane = tid & 63, wid = tid >> 6;
  const int lm = lane & 15, q = lane >> 4;
  const int wm = wid >> 1, wn = wid & 1;
  const long row0 = (long)blockIdx.x * 128;
  const long col0 = (long)blockIdx.y * 128;
  const int z = blockIdx.z;
  A += (long)z * K;
  Bt += (long)z * K;

  floatx4 acc[4][4] = {};

  // staging map: issue (rh,kk): thread t -> row rh*64 + t/4, k-col kk*32 + (t&3)*8
  const int trow = tid >> 2;        // 0..63
  const int tcol = (tid & 3) * 8;
  const ushort_t* Ag = A + (row0 + trow) * (long)kstride + tcol;
  const ushort_t* Bg = Bt + (col0 + trow) * (long)kstride + tcol;
  const long rstep = 64L * kstride;

  for (int k0 = 0; k0 < K; k0 += 64) {
#pragma unroll
    for (int kk = 0; kk < 2; kk++)
#pragma unroll
      for (int rh = 0; rh < 2; rh++) {
        g2l16(Ag + rh * rstep + k0 + kk * 32, sA + kk * 4096 + rh * 2048 + wid * 512);
        g2l16(Bg + rh * rstep + k0 + kk * 32, sB + kk * 4096 + rh * 2048 + wid * 512);
      }
    __syncthreads();
#pragma unroll
    for (int kk = 0; kk < 2; kk++) {
      bf16x8 af[4], bfr[4];
#pragma unroll
      for (int i = 0; i < 4; i++)
        af[i] = *(const bf16x8*)(const void*)&sA[kk * 4096 + (wm * 64 + i * 16 + lm) * 32 + q * 8];
#pragma unroll
      for (int j = 0; j < 4; j++)
        bfr[j] = *(const bf16x8*)(const void*)&sB[kk * 4096 + (wn * 64 + j * 16 + lm) * 32 + q * 8];
#pragma unroll
      for (int i = 0; i < 4; i++)
#pragma unroll
        for (int j = 0; j < 4; j++)
          acc[i][j] = __builtin_amdgcn_mfma_f32_16x16x32_bf16(af[i], bfr[j], acc[i][j], 0, 0, 0);
    }
    __syncthreads();
  }
#pragma unroll
  for (int i = 0; i < 4; i++) {
#pragma unroll
    for (int r = 0; r < 4; r++) {
      long row = row0 + wm * 64 + i * 16 + q * 4 + r;
#pragma unroll
      for (int j = 0; j < 4; j++) {
        long col = col0 + wn * 64 + j * 16 + lm;
        float v = acc[i][j][r];
        if (MODE == 0) {
          ((ushort_t*)Cout)[row * (long)ldc + col] = f2b(v);
        } else {
          ((float*)Cout)[(long)z * zoff + row * (long)ldc + col] = v;
        }
      }
    }
  }
}

// ---------------- split-K combine kernels ----------------
// lat = f2b(10*tanh(0.1 * sum_z P))   (down-proj epilogue)
__global__ __launch_bounds__(256) void k_comb_tanh(const float* __restrict__ P, long zoff, int nz,
                                                   ushort_t* __restrict__ lat) {
  long i = ((long)blockIdx.x * 256 + threadIdx.x) * 4;
  float s[4] = {0, 0, 0, 0};
  for (int zz = 0; zz < nz; zz++) {
    const float* p = P + (long)zz * zoff + i;
#pragma unroll
    for (int j = 0; j < 4; j++) s[j] += p[j];
  }
#pragma unroll
  for (int j = 0; j < 4; j++) lat[i + j] = f2b(10.0f * fast_tanh(0.1f * s[j]));
}

// out(f32) = b2f(x1) + ls2 * sum_z P   (up-proj epilogue)
__global__ __launch_bounds__(256) void k_comb_out(const float* __restrict__ P, long zoff, int nz,
                                                  const ushort_t* __restrict__ x1,
                                                  const float* __restrict__ ls,
                                                  float* __restrict__ outp) {
  long i = ((long)blockIdx.x * 256 + threadIdx.x) * 4;
  float s[4] = {0, 0, 0, 0};
  for (int zz = 0; zz < nz; zz++) {
    const float* p = P + (long)zz * zoff + i;
#pragma unroll
    for (int j = 0; j < 4; j++) s[j] += p[j];
  }
  int c = (int)(i % DD);
#pragma unroll
  for (int j = 0; j < 4; j++) outp[i + j] = b2f(x1[i + j]) + ls[c + j] * s[j];
}

// ---------------- workspace layout (bytes), peak ~124.9 MB ----------------
#define OFF_WINT   0L                          // 9,633,792
#define OFF_WOUTT  9633792L                    // 4,718,592
#define OFF_WDNT   14352384L                   // 393,216
#define OFF_WUPT   14745600L                   // 1,572,864
#define OFF_GT     16318464L                   // 4,194,304
#define OFF_X1     20512768L                   // 12,582,912
#define OFF_WRT    33095680L                   // 262,144
#define OFF_SSUM   34144256L                   // 786,432
#define OFF_ASUM   34930688L                   // 12,288
#define OFF_CARRY  34942976L                   // 786,432
#define OFF_XN     35729408L                   // 12,582,912 (alias x2n)
#define OFF_Y      48312320L                   // 25,165,824 (alias moe)
#define OFF_PROJ   73478144L                   // 51,380,224 (alias abig+lat, split-K partials)
#define OFF_ABIG   OFF_PROJ
#define OFF_LAT    (OFF_PROJ + 33554432L)
#define OFF_PART   OFF_PROJ                    // split-K partials (<= 50.3 MB, proj dead)
#define OFF_X2N    OFF_XN
#define OFF_MOE    OFF_Y
#define WS_NEEDED  124858368L

extern "C" void kernel_launch(void* const* d_in, const int* in_sizes, int n_in,
                              void* d_out, int out_size, void* d_ws, size_t ws_size,
                              hipStream_t stream) {
  const float* x     = (const float*)d_in[0];
  const float* rms1w = (const float*)d_in[1];
  const float* W_in  = (const float*)d_in[2];
  const float* dtb   = (const float*)d_in[3];
  const float* W_out = (const float*)d_in[4];
  const float* ls1   = (const float*)d_in[5];
  const float* rms2w = (const float*)d_in[6];
  const float* W_dn  = (const float*)d_in[7];
  const float* W_rtr = (const float*)d_in[8];
  const float* G     = (const float*)d_in[9];
  const float* W_up  = (const float*)d_in[10];
  const float* ls2   = (const float*)d_in[11];
  if (ws_size < (size_t)WS_NEEDED) return;

  char* ws = (char*)d_ws;
  ushort_t* W_inT  = (ushort_t*)(ws + OFF_WINT);
  ushort_t* W_outT = (ushort_t*)(ws + OFF_WOUTT);
  ushort_t* W_dnT  = (ushort_t*)(ws + OFF_WDNT);
  ushort_t* W_upT  = (ushort_t*)(ws + OFF_WUPT);
  ushort_t* GT     = (ushort_t*)(ws + OFF_GT);
  ushort_t* x1     = (ushort_t*)(ws + OFF_X1);
  float*    wrt    = (float*)(ws + OFF_WRT);
  float*    ssum   = (float*)(ws + OFF_SSUM);
  float*    asum   = (float*)(ws + OFF_ASUM);
  float*    carry  = (float*)(ws + OFF_CARRY);
  ushort_t* xn     = (ushort_t*)(ws + OFF_XN);
  ushort_t* y      = (ushort_t*)(ws + OFF_Y);
  ushort_t* proj   = (ushort_t*)(ws + OFF_PROJ);
  ushort_t* abig   = (ushort_t*)(ws + OFF_ABIG);
  ushort_t* lat    = (ushort_t*)(ws + OFF_LAT);
  float*    part   = (float*)(ws + OFF_PART);
  ushort_t* x2n    = (ushort_t*)(ws + OFF_X2N);
  ushort_t* moe    = (ushort_t*)(ws + OFF_MOE);
  float*    outp   = (float*)d_out;

  // all 5 weight transposes in one launch (f32 -> bf16, [K][N] -> [N][K])
  k_tr_all<<<2504, 256, 0, stream>>>(W_in, W_inT, W_out, W_outT, W_dn, W_dnT,
                                     W_up, W_upT, G, GT);
  k_rms<<<8192, 256, 0, stream>>>(x, rms1w, xn);

  for (int b = 0; b < 2; b++) {
    const ushort_t* xnb = xn + (long)b * LB * DD;
    // in-proj: M=4096, N=6272, K=768 (1568 blocks, 12 K-iters)
    k_gemm<0><<<dim3(32, 49, 1), 256, 0, stream>>>(xnb, W_inT, proj, 768, 768, (int)NP, 0);
    k_scan1<<<3072, 64, 0, stream>>>(proj, dtb, ssum, asum);
    k_scan2<<<48, 64, 0, stream>>>(ssum, asum, carry);
    k_scan3<<<3072, 64, 0, stream>>>(proj, dtb, carry, y);
    // out-proj split-K z=4: M=4096, N=768, K=3072 -> 768 blocks
    k_gemm<4><<<dim3(32, 6, 4), 256, 0, stream>>>(y, W_outT, part, 768, 3072, 768, LB * DD);
    // fused combine + rmsnorm2 + router
    k_fuse2<<<4096, 256, 0, stream>>>(part, x + (long)b * LB * DD, ls1, rms2w, W_rtr,
                                      x1 + (long)b * LB * DD, x2n + (long)b * LB * DD,
                                      wrt + (long)b * LB * 8);
  }

  // down-proj split-K z=3: M=8192, N=256, K=768 -> 384 blocks
  k_gemm<4><<<dim3(64, 2, 3), 256, 0, stream>>>(x2n, W_dnT, part, 256, 768, 256, TT * R3C);
  k_comb_tanh<<<2048, 256, 0, stream>>>(part, TT * R3C, 3, lat);
  k_abig<<<16384, 256, 0, stream>>>(lat, wrt, abig);
  // MoE: M=8192, N=1024, K=2048 (512 blocks, 32 K-iters)
  k_gemm<0><<<dim3(64, 8, 1), 256, 0, stream>>>(abig, GT, moe, 2048, 2048, 1024, 0);
  // up-proj split-K z=2: M=8192, N=768, K=1024 -> 768 blocks
  k_gemm<4><<<dim3(64, 6, 2), 256, 0, stream>>>(moe, W_upT, part, 512, 1024, 768, TT * DD);
  k_comb_out<<<6144, 256, 0, stream>>>(part, TT * DD, 2, x1, ls2, outp);
}